// Round 1
// baseline (835.905 us; speedup 1.0000x reference)
//
#include <hip/hip_runtime.h>

// ---------------------------------------------------------------------------
// Graph multi-head attention conv, CSR-grouped, bf16 k/v.
//   N=100000, E=1600000, H=8, C=16, DIM=128, EDGE_DIM=32
// Stages:
//   1) qkv_count_kernel: grid (nb,7). y<6: tiled fp32 SGEMM (transposed-LDS,
//      ds_read_b128 fragments); q stored fp32, k/v stored bf16 in epilogue.
//      y==6: dst-degree histogram (int4 loads + L2 atomics) — hides under GEMM.
//   2) 3-kernel hierarchical exclusive scan -> offsets/cursor.
//   3) scatter: perm[pos] = int2(src, e)  (8B packed writes).
//   4) attn_fused: one wave per dst. Per-edge (src,e) broadcast via
//      v_readlane -> SGPR (uniform) so k/v/edge_attr gathers use SGPR-base +
//      constant lane voffset (SALU addressing, no ds_bpermute). 2x4-edge
//      ping-pong register pipeline gives ~8-edge prefetch distance to cover
//      L3/HBM gather latency. Single coalesced 512B row write, no atomics.
// Softmax max-subtraction skipped (alpha invariant; scores O(10)).
// ---------------------------------------------------------------------------

typedef unsigned int uint32;

__device__ inline unsigned short f2bf(float f) {  // round-to-nearest-even
    uint32 u = __float_as_uint(f);
    uint32 r = u + 0x7fffu + ((u >> 16) & 1u);
    return (unsigned short)(r >> 16);
}

__global__ __launch_bounds__(256) void qkv_count_kernel(
    const float* __restrict__ x,
    const float* __restrict__ Wq,
    const float* __restrict__ Wk,
    const float* __restrict__ Wv,
    const int* __restrict__ edge_index,
    float* __restrict__ q,            // [N][128] fp32
    unsigned short* __restrict__ kbf, // [N][128] bf16
    unsigned short* __restrict__ vbf, // [N][128] bf16
    int* __restrict__ counts,
    int N, int E)
{
    if (blockIdx.y == 6) {
        // ---- degree histogram, 4 edges/thread ----
        int idx = blockIdx.x * 256 + threadIdx.x;
        if (idx * 4 + 3 < E) {
            int4 d4 = ((const int4*)(edge_index + E))[idx];
            atomicAdd(&counts[d4.x], 1);
            atomicAdd(&counts[d4.y], 1);
            atomicAdd(&counts[d4.z], 1);
            atomicAdd(&counts[d4.w], 1);
        } else {
            for (int e = idx * 4; e < E; ++e)
                atomicAdd(&counts[edge_index[(size_t)E + e]], 1);
        }
        return;
    }

    const int nb = blockIdx.x * 64;
    const int cb = blockIdx.y * 64;
    const float* __restrict__ W = (cb < 128) ? Wq : (cb < 256) ? Wk : Wv;
    const int wrow0 = cb & 127;

    // transposed tiles: [kk][row], pad 68 keeps 16B alignment, conflicts <=2-way
    __shared__ float As[16][68];
    __shared__ float Bs[16][68];

    const int tid = threadIdx.x;
    const int tx = tid & 15;
    const int ty = tid >> 4;

    float acc[4][4] = {};

    const int lrow = tid >> 2;
    const int lk   = (tid & 3) * 4;
    const int n_load = nb + lrow;

    for (int k0 = 0; k0 < 128; k0 += 16) {
        float4 a = make_float4(0.f, 0.f, 0.f, 0.f);
        if (n_load < N)
            a = *(const float4*)(x + (size_t)n_load * 128 + k0 + lk);
        float4 b = *(const float4*)(W + (size_t)(wrow0 + lrow) * 128 + k0 + lk);
        As[lk + 0][lrow] = a.x; As[lk + 1][lrow] = a.y;
        As[lk + 2][lrow] = a.z; As[lk + 3][lrow] = a.w;
        Bs[lk + 0][lrow] = b.x; Bs[lk + 1][lrow] = b.y;
        Bs[lk + 2][lrow] = b.z; Bs[lk + 3][lrow] = b.w;
        __syncthreads();
#pragma unroll
        for (int kk = 0; kk < 16; ++kk) {
            float4 av = *(const float4*)&As[kk][ty * 4];
            float4 bv = *(const float4*)&Bs[kk][tx * 4];
            float avr[4] = {av.x, av.y, av.z, av.w};
            float bvr[4] = {bv.x, bv.y, bv.z, bv.w};
#pragma unroll
            for (int i = 0; i < 4; ++i)
#pragma unroll
                for (int j = 0; j < 4; ++j)
                    acc[i][j] = fmaf(avr[i], bvr[j], acc[i][j]);
        }
        __syncthreads();
    }

#pragma unroll
    for (int i = 0; i < 4; ++i) {
        int n = nb + ty * 4 + i;
        if (n >= N) continue;
        if (cb < 128) {
            float4 o = make_float4(acc[i][0], acc[i][1], acc[i][2], acc[i][3]);
            *(float4*)(q + (size_t)n * 128 + wrow0 + tx * 4) = o;
        } else {
            unsigned short* kv = (cb < 256) ? kbf : vbf;
            ushort4 o;
            o.x = f2bf(acc[i][0]); o.y = f2bf(acc[i][1]);
            o.z = f2bf(acc[i][2]); o.w = f2bf(acc[i][3]);
            *(ushort4*)(kv + (size_t)n * 128 + wrow0 + tx * 4) = o;
        }
    }
}

__global__ __launch_bounds__(256) void scan_pass1(
    const int* __restrict__ counts, int* __restrict__ blocksums, int N)
{
    __shared__ int red[256];
    int base = blockIdx.x * 512;
    int t = threadIdx.x;
    int s = 0;
    if (base + t < N)       s += counts[base + t];
    if (base + 256 + t < N) s += counts[base + 256 + t];
    red[t] = s;
    __syncthreads();
    for (int off = 128; off > 0; off >>= 1) {
        if (t < off) red[t] += red[t + off];
        __syncthreads();
    }
    if (t == 0) blocksums[blockIdx.x] = red[0];
}

__global__ __launch_bounds__(256) void scan_pass2(
    const int* __restrict__ blocksums, int* __restrict__ blockbase, int NB)
{
    __shared__ int sc[256];
    int t = threadIdx.x;
    int v = (t < NB) ? blocksums[t] : 0;
    sc[t] = v;
    __syncthreads();
    for (int off = 1; off < 256; off <<= 1) {
        int tmp = (t >= off) ? sc[t - off] : 0;
        __syncthreads();
        sc[t] += tmp;
        __syncthreads();
    }
    if (t < NB) blockbase[t] = sc[t] - v;  // exclusive
}

__global__ __launch_bounds__(256) void scan_pass3(
    const int* __restrict__ counts, const int* __restrict__ blockbase,
    int* __restrict__ offsets, int* __restrict__ cursor, int N)
{
    __shared__ int sc[256];
    int base = blockIdx.x * 512;
    int t = threadIdx.x;
    int i0 = base + 2 * t, i1 = i0 + 1;
    int c0 = (i0 < N) ? counts[i0] : 0;
    int c1 = (i1 < N) ? counts[i1] : 0;
    int pair = c0 + c1;
    sc[t] = pair;
    __syncthreads();
    for (int off = 1; off < 256; off <<= 1) {
        int tmp = (t >= off) ? sc[t - off] : 0;
        __syncthreads();
        sc[t] += tmp;
        __syncthreads();
    }
    int ex = sc[t] - pair + blockbase[blockIdx.x];
    if (i0 < N) { offsets[i0] = ex;      cursor[i0] = ex; }
    if (i1 < N) { offsets[i1] = ex + c0; cursor[i1] = ex + c0; }
}

__global__ __launch_bounds__(256) void scatter_kernel(
    const int* __restrict__ edge_index,
    int* __restrict__ cursor,
    int2* __restrict__ perm,
    int E)
{
    int e = blockIdx.x * 256 + threadIdx.x;
    if (e >= E) return;
    int s = edge_index[e];
    int d = edge_index[(size_t)E + e];
    int pos = atomicAdd(&cursor[d], 1);
    perm[pos] = make_int2(s, e);
}

__global__ __launch_bounds__(256) void attn_fused_kernel(
    const float* __restrict__ q,
    const unsigned short* __restrict__ kbf,
    const unsigned short* __restrict__ vbf,
    const float* __restrict__ edge_attr,  // [E][32]
    const float* __restrict__ We,         // [8][32]
    const int* __restrict__ offsets,
    const int* __restrict__ counts,
    const int2* __restrict__ perm,
    float* __restrict__ out,              // [N][128]
    int N)
{
    const int d    = blockIdx.x * 4 + (threadIdx.x >> 6);
    const int lane = threadIdx.x & 63;
    if (d >= N) return;
    const int h = lane >> 3;
    const int j = lane & 7;

    const float4 we4 = *(const float4*)(We + h * 32 + j * 4);
    const float2 q2  = *(const float2*)(q + (size_t)d * 128 + lane * 2);
    // fold 1/sqrt(C)=0.25 into q (reduction over lanes is linear)
    const float qx = q2.x * 0.25f;
    const float qy = q2.y * 0.25f;

    const int start = offsets[d];
    const int cnt   = counts[d];

    float denom = 0.f, accx = 0.f, accy = 0.f;

    const int laneb = lane * 4;  // byte offset of this lane's dword in a k/v row
    const char* kbp = (const char*)kbf;
    const char* vbp = (const char*)vbf;

    for (int i0 = 0; i0 < cnt; i0 += 64) {
        const int m = min(64, cnt - i0);
        int2 pv = make_int2(0, 0);
        if (lane < m) pv = perm[start + i0 + lane];

        // ---- 2x4-edge ping-pong register pipeline ----
        uint32 ka[4], va[4]; float4 ea[4];
        uint32 kc[4], vc[4]; float4 ec[4];

        // readlane -> SGPR src/e: loads get SGPR base + constant lane voffset.
#define LOADG(AK, AV, AE, T0)                                                  \
        _Pragma("unroll")                                                      \
        for (int u = 0; u < 4; ++u) {                                          \
            int t = (T0) + u;                                                  \
            if (t < m) {                                                       \
                int src = __builtin_amdgcn_readlane(pv.x, t);                  \
                int e   = __builtin_amdgcn_readlane(pv.y, t);                  \
                AK[u] = *(const uint32*)(kbp + ((size_t)src << 8) + laneb);    \
                AV[u] = *(const uint32*)(vbp + ((size_t)src << 8) + laneb);    \
                AE[u] = *(const float4*)(edge_attr + (size_t)e * 32 + j * 4);  \
            }                                                                  \
        }

#define COMPG(AK, AV, AE, T0)                                                  \
        _Pragma("unroll")                                                      \
        for (int u = 0; u < 4; ++u) {                                          \
            int t = (T0) + u;                                                  \
            if (t < m) {                                                       \
                float kx = __uint_as_float(AK[u] << 16);                       \
                float ky = __uint_as_float(AK[u] & 0xffff0000u);               \
                float4 ce = AE[u];                                             \
                float part = qx * kx + qy * ky                                 \
                           + ce.x * we4.x + ce.y * we4.y                       \
                           + ce.z * we4.z + ce.w * we4.w;                      \
                part += __shfl_xor(part, 1);                                   \
                part += __shfl_xor(part, 2);                                   \
                part += __shfl_xor(part, 4);                                   \
                float ev = __expf(part);                                       \
                denom += ev;                                                   \
                accx = fmaf(ev, __uint_as_float(AV[u] << 16), accx);           \
                accy = fmaf(ev, __uint_as_float(AV[u] & 0xffff0000u), accy);   \
            }                                                                  \
        }

        LOADG(ka, va, ea, 0)
        LOADG(kc, vc, ec, 4)
        for (int t0 = 0; t0 < m; t0 += 8) {
            COMPG(ka, va, ea, t0)          // consume A
            LOADG(ka, va, ea, t0 + 8)      // refill A for t0+8 (guarded)
            COMPG(kc, vc, ec, t0 + 4)      // consume B
            LOADG(kc, vc, ec, t0 + 12)     // refill B for t0+12 (guarded)
        }
#undef LOADG
#undef COMPG
    }

    float inv = denom > 0.f ? 1.f / denom : 0.f;
    *(float2*)(out + (size_t)d * 128 + lane * 2) = make_float2(accx * inv, accy * inv);
}

extern "C" void kernel_launch(void* const* d_in, const int* in_sizes, int n_in,
                              void* d_out, int out_size, void* d_ws, size_t ws_size,
                              hipStream_t stream) {
    const float* x          = (const float*)d_in[0];
    const int*   edge_index = (const int*)d_in[1];
    const float* edge_attr  = (const float*)d_in[2];
    const float* Wq         = (const float*)d_in[3];
    const float* Wk         = (const float*)d_in[4];
    const float* Wv         = (const float*)d_in[5];
    const float* We         = (const float*)d_in[6];
    float* out = (float*)d_out;

    const int N = in_sizes[0] / 128;
    const int E = in_sizes[1] / 2;

    // ws layout: q f32[N*128] | kbf,vbf bf16[N*128] | perm int2[E] |
    //            counts,offsets,cursor[N] | blocksums,blockbase[256]
    float* q = (float*)d_ws;
    unsigned short* kbf = (unsigned short*)(q + (size_t)N * 128);
    unsigned short* vbf = kbf + (size_t)N * 128;
    int2* perm = (int2*)(vbf + (size_t)N * 128);
    int* counts    = (int*)(perm + E);
    int* offsets   = counts + N;
    int* cursor    = offsets + N;
    int* blocksums = cursor + N;
    int* blockbase = blocksums + 256;

    hipMemsetAsync(counts, 0, (size_t)N * sizeof(int), stream);

    const int nxb = (N + 63) / 64;  // 1563
    dim3 g1(nxb, 7);                // y<6: GEMM, y==6: histogram
    qkv_count_kernel<<<g1, 256, 0, stream>>>(x, Wq, Wk, Wv, edge_index,
                                             q, kbf, vbf, counts, N, E);

    const int NB = (N + 511) / 512;  // 196
    scan_pass1<<<NB, 256, 0, stream>>>(counts, blocksums, N);
    scan_pass2<<<1, 256, 0, stream>>>(blocksums, blockbase, NB);
    scan_pass3<<<NB, 256, 0, stream>>>(counts, blockbase, offsets, cursor, N);

    scatter_kernel<<<(E + 255) / 256, 256, 0, stream>>>(edge_index, cursor,
                                                        perm, E);

    attn_fused_kernel<<<(N + 3) / 4, 256, 0, stream>>>(
        q, kbf, vbf, edge_attr, We, offsets, counts, perm, out, N);
}

// Round 3
// 829.777 us; speedup vs baseline: 1.0074x; 1.0074x over previous
//
#include <hip/hip_runtime.h>

// ---------------------------------------------------------------------------
// Graph multi-head attention conv, CSR-grouped, bf16 k/v.
//   N=100000, E=1600000, H=8, C=16, DIM=128, EDGE_DIM=32
// Stages:
//   1) qkv_count_kernel: grid (nb,7|8). y<6: tiled fp32 SGEMM (transposed-LDS,
//      ds_read_b128 fragments); q stored fp32, k/v stored bf16 in epilogue.
//      y==6: dst-degree histogram (int4 loads + L2 atomics) — hides under GEMM.
//      y==7 (only if ws_size permits): edge bias precompute
//      ebias[e][h] = edge_attr[e]·We[h], coalesced; hides under GEMM.
//   2) 3-kernel hierarchical exclusive scan -> offsets/cursor.
//   3) scatter: perm[pos] = int2(src, e)  (8B packed writes).
//   4) attn_fused<USE_BIAS>: one wave per dst; perm batch-loaded + __shfl
//      broadcast, next-edge k/v/(bias|ea) prefetched before use (1-edge
//      pipeline, the proven round-0 schedule); bf16 k/v; 8-lane score reduce
//      via DPP butterfly (quad_perm xor1/xor2 + row_half_mirror) — pure VALU,
//      no LDS pipe. Single coalesced 512B row write. No atomics in hot path.
// ws-size guard: ebias (51.2MB) is only used if it fits inside d_ws —
// round-2's container fault is suspected OOB ws write.
// Softmax max-subtraction skipped (alpha invariant; scores O(10)).
// ---------------------------------------------------------------------------

typedef unsigned int uint32;

__device__ inline unsigned short f2bf(float f) {  // round-to-nearest-even
    uint32 u = __float_as_uint(f);
    uint32 r = u + 0x7fffu + ((u >> 16) & 1u);
    return (unsigned short)(r >> 16);
}

template <int CTRL>
__device__ inline float dpp_mov(float v) {
    return __int_as_float(__builtin_amdgcn_update_dpp(
        0, __float_as_int(v), CTRL, 0xF, 0xF, true));
}

__global__ __launch_bounds__(256) void qkv_count_kernel(
    const float* __restrict__ x,
    const float* __restrict__ Wq,
    const float* __restrict__ Wk,
    const float* __restrict__ Wv,
    const float* __restrict__ We,         // [8][32]
    const float* __restrict__ edge_attr,  // [E][32]
    const int* __restrict__ edge_index,
    float* __restrict__ q,            // [N][128] fp32
    unsigned short* __restrict__ kbf, // [N][128] bf16
    unsigned short* __restrict__ vbf, // [N][128] bf16
    float* __restrict__ ebias,        // [E][8] fp32 (may be unused)
    int* __restrict__ counts,
    int N, int E)
{
    if (blockIdx.y == 6) {
        // ---- degree histogram, 4 edges/thread ----
        int idx = blockIdx.x * 256 + threadIdx.x;
        if (idx * 4 + 3 < E) {
            int4 d4 = ((const int4*)(edge_index + E))[idx];
            atomicAdd(&counts[d4.x], 1);
            atomicAdd(&counts[d4.y], 1);
            atomicAdd(&counts[d4.z], 1);
            atomicAdd(&counts[d4.w], 1);
        } else {
            for (int e = idx * 4; e < E; ++e)
                atomicAdd(&counts[edge_index[(size_t)E + e]], 1);
        }
        return;
    }

    if (blockIdx.y == 7) {
        // ---- edge bias: thread = (edge_slot, head); We row held in regs ----
        const int t  = threadIdx.x;
        const int h  = t & 7;
        const int er = t >> 3;            // 0..31
        float4 wreg[8];
#pragma unroll
        for (int i = 0; i < 8; ++i)
            wreg[i] = *(const float4*)(We + h * 32 + i * 4);
        const int e0 = blockIdx.x * 1024;
        for (int it = 0; it < 32; ++it) {
            int e = e0 + it * 32 + er;
            if (e < E) {
                const float* ea = edge_attr + (size_t)e * 32;
                float s = 0.f;
#pragma unroll
                for (int i = 0; i < 8; ++i) {
                    float4 a = *(const float4*)(ea + i * 4);
                    float4 w = wreg[i];
                    s += a.x * w.x + a.y * w.y + a.z * w.z + a.w * w.w;
                }
                ebias[(size_t)e * 8 + h] = s;  // contiguous across the block
            }
        }
        return;
    }

    const int nb = blockIdx.x * 64;
    const int cb = blockIdx.y * 64;
    const float* __restrict__ W = (cb < 128) ? Wq : (cb < 256) ? Wk : Wv;
    const int wrow0 = cb & 127;

    // transposed tiles: [kk][row], pad 68 keeps 16B alignment, conflicts <=2-way
    __shared__ float As[16][68];
    __shared__ float Bs[16][68];

    const int tid = threadIdx.x;
    const int tx = tid & 15;
    const int ty = tid >> 4;

    float acc[4][4] = {};

    const int lrow = tid >> 2;
    const int lk   = (tid & 3) * 4;
    const int n_load = nb + lrow;

    for (int k0 = 0; k0 < 128; k0 += 16) {
        float4 a = make_float4(0.f, 0.f, 0.f, 0.f);
        if (n_load < N)
            a = *(const float4*)(x + (size_t)n_load * 128 + k0 + lk);
        float4 b = *(const float4*)(W + (size_t)(wrow0 + lrow) * 128 + k0 + lk);
        As[lk + 0][lrow] = a.x; As[lk + 1][lrow] = a.y;
        As[lk + 2][lrow] = a.z; As[lk + 3][lrow] = a.w;
        Bs[lk + 0][lrow] = b.x; Bs[lk + 1][lrow] = b.y;
        Bs[lk + 2][lrow] = b.z; Bs[lk + 3][lrow] = b.w;
        __syncthreads();
#pragma unroll
        for (int kk = 0; kk < 16; ++kk) {
            float4 av = *(const float4*)&As[kk][ty * 4];
            float4 bv = *(const float4*)&Bs[kk][tx * 4];
            float avr[4] = {av.x, av.y, av.z, av.w};
            float bvr[4] = {bv.x, bv.y, bv.z, bv.w};
#pragma unroll
            for (int i = 0; i < 4; ++i)
#pragma unroll
                for (int j = 0; j < 4; ++j)
                    acc[i][j] = fmaf(avr[i], bvr[j], acc[i][j]);
        }
        __syncthreads();
    }

#pragma unroll
    for (int i = 0; i < 4; ++i) {
        int n = nb + ty * 4 + i;
        if (n >= N) continue;
        if (cb < 128) {
            float4 o = make_float4(acc[i][0], acc[i][1], acc[i][2], acc[i][3]);
            *(float4*)(q + (size_t)n * 128 + wrow0 + tx * 4) = o;
        } else {
            unsigned short* kv = (cb < 256) ? kbf : vbf;
            ushort4 o;
            o.x = f2bf(acc[i][0]); o.y = f2bf(acc[i][1]);
            o.z = f2bf(acc[i][2]); o.w = f2bf(acc[i][3]);
            *(ushort4*)(kv + (size_t)n * 128 + wrow0 + tx * 4) = o;
        }
    }
}

__global__ __launch_bounds__(256) void scan_pass1(
    const int* __restrict__ counts, int* __restrict__ blocksums, int N)
{
    __shared__ int red[256];
    int base = blockIdx.x * 512;
    int t = threadIdx.x;
    int s = 0;
    if (base + t < N)       s += counts[base + t];
    if (base + 256 + t < N) s += counts[base + 256 + t];
    red[t] = s;
    __syncthreads();
    for (int off = 128; off > 0; off >>= 1) {
        if (t < off) red[t] += red[t + off];
        __syncthreads();
    }
    if (t == 0) blocksums[blockIdx.x] = red[0];
}

__global__ __launch_bounds__(256) void scan_pass2(
    const int* __restrict__ blocksums, int* __restrict__ blockbase, int NB)
{
    __shared__ int sc[256];
    int t = threadIdx.x;
    int v = (t < NB) ? blocksums[t] : 0;
    sc[t] = v;
    __syncthreads();
    for (int off = 1; off < 256; off <<= 1) {
        int tmp = (t >= off) ? sc[t - off] : 0;
        __syncthreads();
        sc[t] += tmp;
        __syncthreads();
    }
    if (t < NB) blockbase[t] = sc[t] - v;  // exclusive
}

__global__ __launch_bounds__(256) void scan_pass3(
    const int* __restrict__ counts, const int* __restrict__ blockbase,
    int* __restrict__ offsets, int* __restrict__ cursor, int N)
{
    __shared__ int sc[256];
    int base = blockIdx.x * 512;
    int t = threadIdx.x;
    int i0 = base + 2 * t, i1 = i0 + 1;
    int c0 = (i0 < N) ? counts[i0] : 0;
    int c1 = (i1 < N) ? counts[i1] : 0;
    int pair = c0 + c1;
    sc[t] = pair;
    __syncthreads();
    for (int off = 1; off < 256; off <<= 1) {
        int tmp = (t >= off) ? sc[t - off] : 0;
        __syncthreads();
        sc[t] += tmp;
        __syncthreads();
    }
    int ex = sc[t] - pair + blockbase[blockIdx.x];
    if (i0 < N) { offsets[i0] = ex;      cursor[i0] = ex; }
    if (i1 < N) { offsets[i1] = ex + c0; cursor[i1] = ex + c0; }
}

__global__ __launch_bounds__(256) void scatter_kernel(
    const int* __restrict__ edge_index,
    int* __restrict__ cursor,
    int2* __restrict__ perm,
    int E)
{
    int e = blockIdx.x * 256 + threadIdx.x;
    if (e >= E) return;
    int s = edge_index[e];
    int d = edge_index[(size_t)E + e];
    int pos = atomicAdd(&cursor[d], 1);
    perm[pos] = make_int2(s, e);
}

template <bool USE_BIAS>
__global__ __launch_bounds__(256) void attn_fused_kernel(
    const float* __restrict__ q,
    const unsigned short* __restrict__ kbf,
    const unsigned short* __restrict__ vbf,
    const float* __restrict__ ebias,      // [E][8] fp32 (USE_BIAS)
    const float* __restrict__ edge_attr,  // [E][32]     (!USE_BIAS)
    const float* __restrict__ We,         // [8][32]     (!USE_BIAS)
    const int* __restrict__ offsets,
    const int* __restrict__ counts,
    const int2* __restrict__ perm,
    float* __restrict__ out,              // [N][128]
    int N)
{
    const int d    = blockIdx.x * 4 + (threadIdx.x >> 6);
    const int lane = threadIdx.x & 63;
    if (d >= N) return;
    const int h = lane >> 3;
    const int j = lane & 7;

    float4 we4 = make_float4(0.f, 0.f, 0.f, 0.f);
    if (!USE_BIAS) we4 = *(const float4*)(We + h * 32 + j * 4);

    const float2 q2 = *(const float2*)(q + (size_t)d * 128 + lane * 2);
    // fold 1/sqrt(C)=0.25 into q (reduction over lanes is linear)
    const float qx = q2.x * 0.25f;
    const float qy = q2.y * 0.25f;

    const int start = offsets[d];
    const int cnt   = counts[d];

    float denom = 0.f, accx = 0.f, accy = 0.f;

    for (int i0 = 0; i0 < cnt; i0 += 64) {
        int m = min(64, cnt - i0);
        int2 pv = make_int2(0, 0);
        if (lane < m) pv = perm[start + i0 + lane];

        // prefetch edge 0
        int src = __shfl(pv.x, 0), e = __shfl(pv.y, 0);
        uint32 kk2 = *(const uint32*)(kbf + (size_t)src * 128 + lane * 2);
        uint32 vv2 = *(const uint32*)(vbf + (size_t)src * 128 + lane * 2);
        float bias = 0.f;
        float4 ea  = make_float4(0.f, 0.f, 0.f, 0.f);
        if (USE_BIAS) bias = ebias[(size_t)e * 8 + h];
        else          ea   = *(const float4*)(edge_attr + (size_t)e * 32 + j * 4);

        for (int t = 0; t < m; ++t) {
            uint32 ck = kk2, cv = vv2;
            float cb = bias;
            float4 cea = ea;
            if (t + 1 < m) {
                int ns = __shfl(pv.x, t + 1), ne = __shfl(pv.y, t + 1);
                kk2 = *(const uint32*)(kbf + (size_t)ns * 128 + lane * 2);
                vv2 = *(const uint32*)(vbf + (size_t)ns * 128 + lane * 2);
                if (USE_BIAS) bias = ebias[(size_t)ne * 8 + h];
                else          ea   = *(const float4*)(edge_attr + (size_t)ne * 32 + j * 4);
            }
            float kx = __uint_as_float(ck << 16);
            float ky = __uint_as_float(ck & 0xffff0000u);
            float part = qx * kx + qy * ky;
            if (!USE_BIAS)
                part += cea.x * we4.x + cea.y * we4.y
                      + cea.z * we4.z + cea.w * we4.w;
            // 8-lane butterfly over aligned head group, all on the VALU pipe:
            part += dpp_mov<0xB1>(part);    // quad_perm [1,0,3,2]  (xor 1)
            part += dpp_mov<0x4E>(part);    // quad_perm [2,3,0,1]  (xor 2)
            part += dpp_mov<0x141>(part);   // row_half_mirror      (quad<->quad)
            float ev = __expf(USE_BIAS ? part + cb : part);
            denom += ev;
            float vx = __uint_as_float(cv << 16);
            float vy = __uint_as_float(cv & 0xffff0000u);
            accx = fmaf(ev, vx, accx);
            accy = fmaf(ev, vy, accy);
        }
    }

    float inv = denom > 0.f ? 1.f / denom : 0.f;
    *(float2*)(out + (size_t)d * 128 + lane * 2) = make_float2(accx * inv, accy * inv);
}

extern "C" void kernel_launch(void* const* d_in, const int* in_sizes, int n_in,
                              void* d_out, int out_size, void* d_ws, size_t ws_size,
                              hipStream_t stream) {
    const float* x          = (const float*)d_in[0];
    const int*   edge_index = (const int*)d_in[1];
    const float* edge_attr  = (const float*)d_in[2];
    const float* Wq         = (const float*)d_in[3];
    const float* Wk         = (const float*)d_in[4];
    const float* Wv         = (const float*)d_in[5];
    const float* We         = (const float*)d_in[6];
    float* out = (float*)d_out;

    const int N = in_sizes[0] / 128;
    const int E = in_sizes[1] / 2;

    // ws layout: q f32[N*128] | kbf,vbf bf16[N*128] | perm int2[E] |
    //            counts,offsets,cursor[N] | blocksums,blockbase[256] |
    //            [ebias f32[E*8] iff it fits in ws_size]
    float* q = (float*)d_ws;
    unsigned short* kbf = (unsigned short*)(q + (size_t)N * 128);
    unsigned short* vbf = kbf + (size_t)N * 128;
    int2* perm = (int2*)(vbf + (size_t)N * 128);
    int* counts    = (int*)(perm + E);
    int* offsets   = counts + N;
    int* cursor    = offsets + N;
    int* blocksums = cursor + N;
    int* blockbase = blocksums + 256;
    float* ebias   = (float*)(blockbase + 256);

    const size_t need_bias =
        (size_t)((char*)(ebias + (size_t)E * 8) - (char*)d_ws);
    const bool use_bias = ws_size >= need_bias;

    hipMemsetAsync(counts, 0, (size_t)N * sizeof(int), stream);

    const int nxb = (N + 63) / 64;  // 1563
    dim3 g1(nxb, use_bias ? 8 : 7); // y<6: GEMM, y==6: histogram, y==7: bias
    qkv_count_kernel<<<g1, 256, 0, stream>>>(x, Wq, Wk, Wv, We, edge_attr,
                                             edge_index, q, kbf, vbf, ebias,
                                             counts, N, E);

    const int NB = (N + 511) / 512;  // 196
    scan_pass1<<<NB, 256, 0, stream>>>(counts, blocksums, N);
    scan_pass2<<<1, 256, 0, stream>>>(blocksums, blockbase, NB);
    scan_pass3<<<NB, 256, 0, stream>>>(counts, blockbase, offsets, cursor, N);

    scatter_kernel<<<(E + 255) / 256, 256, 0, stream>>>(edge_index, cursor,
                                                        perm, E);

    if (use_bias)
        attn_fused_kernel<true><<<(N + 3) / 4, 256, 0, stream>>>(
            q, kbf, vbf, ebias, edge_attr, We, offsets, counts, perm, out, N);
    else
        attn_fused_kernel<false><<<(N + 3) / 4, 256, 0, stream>>>(
            q, kbf, vbf, ebias, edge_attr, We, offsets, counts, perm, out, N);
}

// Round 4
// 764.639 us; speedup vs baseline: 1.0932x; 1.0852x over previous
//
#include <hip/hip_runtime.h>

// ---------------------------------------------------------------------------
// Graph multi-head attention conv, CSR-grouped, bf16 k/v.
//   N=100000, E=1600000, H=8, C=16, DIM=128, EDGE_DIM=32
// Stages:
//   1) qkv_count_kernel: grid (nb,2).
//      y==0: full-row GEMM block — x tile (64x128) staged ONCE in LDS
//            (transposed As[128][68]), then 6 output chunks (q0,q1,k0,k1,v0,v1)
//            with W k-slices double-buffered in Bs[2][16][68] and the next
//            slice prefetched before each compute step (1 barrier/K-step).
//            q stored fp32; k/v packed bf16 INTERLEAVED per lane-pair into
//            kvb[n][128] dwords: pair p -> {k dword @2p, v dword @2p+1}.
//      y==1: dst-degree histogram (int4 loads + L2 atomics).
//   2) 3-kernel hierarchical exclusive scan -> offsets/cursor.
//   3) scatter<WITH_BIAS>: perm[pos]=int2(src,e); bias[8]=edge_attr[e]·We^T
//      computed here (coalesced ea read, scalar We) and written DST-ORDERED
//      to pbias[pos][8] so attn reads it sequentially.
//   4) attn_fused<USE_BIAS>: one wave per dst; perm batch + __shfl broadcast;
//      ONE uint2 gather per edge (interleaved k+v pair); 1-edge prefetch
//      pipeline (proven r0 schedule); 8-lane score reduce via DPP butterfly
//      (quad_perm xor1/xor2 + row_half_mirror, validated r3) — pure VALU.
//      Coalesced 512B row write. No atomics in hot path.
// ws guard: pbias (51.2MB) only used if it fits in d_ws (r2 fault lesson).
// Softmax max-subtraction skipped (alpha invariant; scores O(10)).
// ---------------------------------------------------------------------------

typedef unsigned int uint32;

__device__ inline unsigned short f2bf(float f) {  // round-to-nearest-even
    uint32 u = __float_as_uint(f);
    uint32 r = u + 0x7fffu + ((u >> 16) & 1u);
    return (unsigned short)(r >> 16);
}

__device__ inline uint32 pack2bf(float a, float b) {
    return (uint32)f2bf(a) | ((uint32)f2bf(b) << 16);
}

template <int CTRL>
__device__ inline float dpp_mov(float v) {
    return __int_as_float(__builtin_amdgcn_update_dpp(
        0, __float_as_int(v), CTRL, 0xF, 0xF, true));
}

__global__ __launch_bounds__(256) void qkv_count_kernel(
    const float* __restrict__ x,
    const float* __restrict__ Wq,
    const float* __restrict__ Wk,
    const float* __restrict__ Wv,
    const int* __restrict__ edge_index,
    float* __restrict__ q,            // [N][128] fp32
    uint32* __restrict__ kvb,         // [N][128] dwords, k/v bf16 interleaved
    int* __restrict__ counts,
    int N, int E)
{
    if (blockIdx.y == 1) {
        // ---- degree histogram, 4 edges/thread ----
        int idx = blockIdx.x * 256 + threadIdx.x;
        if (idx * 4 + 3 < E) {
            int4 d4 = ((const int4*)(edge_index + E))[idx];
            atomicAdd(&counts[d4.x], 1);
            atomicAdd(&counts[d4.y], 1);
            atomicAdd(&counts[d4.z], 1);
            atomicAdd(&counts[d4.w], 1);
        } else {
            for (int e = idx * 4; e < E && e >= 0; ++e)
                atomicAdd(&counts[edge_index[(size_t)E + e]], 1);
        }
        return;
    }

    const int nb = blockIdx.x * 64;
    if (nb >= N) return;  // uniform exit before any barrier

    // As: x tile transposed [k][row], staged once. Pad 68 -> 16B-aligned rows,
    // <=2-way conflicts. Bs: W slice [k][wcol], double-buffered.
    __shared__ float As[128][68];
    __shared__ float Bs[2][16][68];

    const int tid = threadIdx.x;
    const int tx = tid & 15;
    const int ty = tid >> 4;
    const int lrow = tid >> 2;
    const int lk   = (tid & 3) * 4;
    const int n_load = nb + lrow;

    // ---- stage full x tile (64 rows x 128 k) ----
#pragma unroll
    for (int k0 = 0; k0 < 128; k0 += 16) {
        float4 a = make_float4(0.f, 0.f, 0.f, 0.f);
        if (n_load < N)
            a = *(const float4*)(x + (size_t)n_load * 128 + k0 + lk);
        As[k0 + lk + 0][lrow] = a.x; As[k0 + lk + 1][lrow] = a.y;
        As[k0 + lk + 2][lrow] = a.z; As[k0 + lk + 3][lrow] = a.w;
    }
    // ---- stage W slice 0 (chunk 0, k0 0) into Bs[0] ----
    {
        float4 b = *(const float4*)(Wq + (size_t)lrow * 128 + lk);
        Bs[0][lk + 0][lrow] = b.x; Bs[0][lk + 1][lrow] = b.y;
        Bs[0][lk + 2][lrow] = b.z; Bs[0][lk + 3][lrow] = b.w;
    }
    __syncthreads();

    // chunks: 0,1 = q[0:64],[64:128]; 2,3 = k; 4,5 = v
#pragma unroll 1
    for (int chunk = 0; chunk < 6; ++chunk) {
        float acc[4][4] = {};
#pragma unroll 2
        for (int k0i = 0; k0i < 8; ++k0i) {
            const int buf = k0i & 1;
            // prefetch next W slice into Bs[buf^1]
            const int idx = chunk * 8 + k0i + 1;
            if (idx < 48) {
                const int nc  = idx >> 3;
                const int nk0 = (idx & 7) * 16;
                const float* __restrict__ W =
                    (nc < 2) ? Wq : (nc < 4) ? Wk : Wv;
                const int wr0 = (nc & 1) * 64;
                float4 b = *(const float4*)(W + (size_t)(wr0 + lrow) * 128
                                            + nk0 + lk);
                Bs[buf ^ 1][lk + 0][lrow] = b.x;
                Bs[buf ^ 1][lk + 1][lrow] = b.y;
                Bs[buf ^ 1][lk + 2][lrow] = b.z;
                Bs[buf ^ 1][lk + 3][lrow] = b.w;
            }
#pragma unroll
            for (int kk = 0; kk < 16; ++kk) {
                float4 av = *(const float4*)&As[k0i * 16 + kk][ty * 4];
                float4 bv = *(const float4*)&Bs[buf][kk][tx * 4];
                float avr[4] = {av.x, av.y, av.z, av.w};
                float bvr[4] = {bv.x, bv.y, bv.z, bv.w};
#pragma unroll
                for (int i = 0; i < 4; ++i)
#pragma unroll
                    for (int j = 0; j < 4; ++j)
                        acc[i][j] = fmaf(avr[i], bvr[j], acc[i][j]);
            }
            __syncthreads();
        }

        // ---- epilogue for this chunk ----
        const int wrow0 = (chunk & 1) * 64;
#pragma unroll
        for (int i = 0; i < 4; ++i) {
            int n = nb + ty * 4 + i;
            if (n >= N) continue;
            if (chunk < 2) {
                float4 o = make_float4(acc[i][0], acc[i][1],
                                       acc[i][2], acc[i][3]);
                *(float4*)(q + (size_t)n * 128 + wrow0 + tx * 4) = o;
            } else {
                const int ch0 = wrow0 + tx * 4;   // even
                uint32* rp = kvb + (size_t)n * 128 + ch0
                           + ((chunk >= 4) ? 1 : 0);
                rp[0] = pack2bf(acc[i][0], acc[i][1]);
                rp[2] = pack2bf(acc[i][2], acc[i][3]);
            }
        }
    }
}

__global__ __launch_bounds__(256) void scan_pass1(
    const int* __restrict__ counts, int* __restrict__ blocksums, int N)
{
    __shared__ int red[256];
    int base = blockIdx.x * 512;
    int t = threadIdx.x;
    int s = 0;
    if (base + t < N)       s += counts[base + t];
    if (base + 256 + t < N) s += counts[base + 256 + t];
    red[t] = s;
    __syncthreads();
    for (int off = 128; off > 0; off >>= 1) {
        if (t < off) red[t] += red[t + off];
        __syncthreads();
    }
    if (t == 0) blocksums[blockIdx.x] = red[0];
}

__global__ __launch_bounds__(256) void scan_pass2(
    const int* __restrict__ blocksums, int* __restrict__ blockbase, int NB)
{
    __shared__ int sc[256];
    int t = threadIdx.x;
    int v = (t < NB) ? blocksums[t] : 0;
    sc[t] = v;
    __syncthreads();
    for (int off = 1; off < 256; off <<= 1) {
        int tmp = (t >= off) ? sc[t - off] : 0;
        __syncthreads();
        sc[t] += tmp;
        __syncthreads();
    }
    if (t < NB) blockbase[t] = sc[t] - v;  // exclusive
}

__global__ __launch_bounds__(256) void scan_pass3(
    const int* __restrict__ counts, const int* __restrict__ blockbase,
    int* __restrict__ offsets, int* __restrict__ cursor, int N)
{
    __shared__ int sc[256];
    int base = blockIdx.x * 512;
    int t = threadIdx.x;
    int i0 = base + 2 * t, i1 = i0 + 1;
    int c0 = (i0 < N) ? counts[i0] : 0;
    int c1 = (i1 < N) ? counts[i1] : 0;
    int pair = c0 + c1;
    sc[t] = pair;
    __syncthreads();
    for (int off = 1; off < 256; off <<= 1) {
        int tmp = (t >= off) ? sc[t - off] : 0;
        __syncthreads();
        sc[t] += tmp;
        __syncthreads();
    }
    int ex = sc[t] - pair + blockbase[blockIdx.x];
    if (i0 < N) { offsets[i0] = ex;      cursor[i0] = ex; }
    if (i1 < N) { offsets[i1] = ex + c0; cursor[i1] = ex + c0; }
}

template <bool WITH_BIAS>
__global__ __launch_bounds__(256) void scatter_kernel(
    const int* __restrict__ edge_index,
    const float* __restrict__ edge_attr,  // [E][32]
    const float* __restrict__ We,         // [8][32]
    int* __restrict__ cursor,
    int2* __restrict__ perm,
    float* __restrict__ pbias,            // [E][8] dst-ordered
    int E)
{
    int e = blockIdx.x * 256 + threadIdx.x;
    if (e >= E) return;
    int s = edge_index[e];
    int d = edge_index[(size_t)E + e];

    float b[8];
    if (WITH_BIAS) {
        const float* ea = edge_attr + (size_t)e * 32;
        float4 a[8];
#pragma unroll
        for (int i = 0; i < 8; ++i) a[i] = *(const float4*)(ea + i * 4);
#pragma unroll
        for (int h = 0; h < 8; ++h) {
            float sum = 0.f;
#pragma unroll
            for (int i = 0; i < 8; ++i) {
                float4 w = *(const float4*)(We + h * 32 + i * 4);  // uniform
                sum += a[i].x * w.x + a[i].y * w.y
                     + a[i].z * w.z + a[i].w * w.w;
            }
            b[h] = sum;
        }
    }

    int pos = atomicAdd(&cursor[d], 1);
    perm[pos] = make_int2(s, e);
    if (WITH_BIAS) {
        float* pb = pbias + (size_t)pos * 8;
        *(float4*)(pb + 0) = make_float4(b[0], b[1], b[2], b[3]);
        *(float4*)(pb + 4) = make_float4(b[4], b[5], b[6], b[7]);
    }
}

template <bool USE_BIAS>
__global__ __launch_bounds__(256) void attn_fused_kernel(
    const float* __restrict__ q,
    const uint32* __restrict__ kvb,       // [N][128] dwords interleaved k/v
    const float* __restrict__ pbias,      // [E][8] dst-ordered (USE_BIAS)
    const float* __restrict__ edge_attr,  // [E][32]  (!USE_BIAS)
    const float* __restrict__ We,         // [8][32]  (!USE_BIAS)
    const int* __restrict__ offsets,
    const int* __restrict__ counts,
    const int2* __restrict__ perm,
    float* __restrict__ out,              // [N][128]
    int N)
{
    const int d    = blockIdx.x * 4 + (threadIdx.x >> 6);
    const int lane = threadIdx.x & 63;
    if (d >= N) return;
    const int h = lane >> 3;
    const int j = lane & 7;

    float4 we4 = make_float4(0.f, 0.f, 0.f, 0.f);
    if (!USE_BIAS) we4 = *(const float4*)(We + h * 32 + j * 4);

    const float2 q2 = *(const float2*)(q + (size_t)d * 128 + lane * 2);
    // fold 1/sqrt(C)=0.25 into q (reduction over lanes is linear)
    const float qx = q2.x * 0.25f;
    const float qy = q2.y * 0.25f;

    const int start = offsets[d];
    const int cnt   = counts[d];

    float denom = 0.f, accx = 0.f, accy = 0.f;

    for (int i0 = 0; i0 < cnt; i0 += 64) {
        int m = min(64, cnt - i0);
        int2 pv = make_int2(0, 0);
        if (lane < m) pv = perm[start + i0 + lane];

        // prefetch edge 0
        int src = __shfl(pv.x, 0), e = __shfl(pv.y, 0);
        uint2 kv = *(const uint2*)(kvb + (size_t)src * 128 + lane * 2);
        float bias = 0.f;
        float4 ea  = make_float4(0.f, 0.f, 0.f, 0.f);
        if (USE_BIAS) bias = pbias[(size_t)(start + i0) * 8 + h];
        else          ea   = *(const float4*)(edge_attr + (size_t)e * 32 + j * 4);

        for (int t = 0; t < m; ++t) {
            uint2 ckv = kv;
            float cb  = bias;
            float4 cea = ea;
            if (t + 1 < m) {
                int ns = __shfl(pv.x, t + 1);
                kv = *(const uint2*)(kvb + (size_t)ns * 128 + lane * 2);
                if (USE_BIAS) {
                    bias = pbias[(size_t)(start + i0 + t + 1) * 8 + h];
                } else {
                    int ne = __shfl(pv.y, t + 1);
                    ea = *(const float4*)(edge_attr + (size_t)ne * 32 + j * 4);
                }
            }
            float kx = __uint_as_float(ckv.x << 16);
            float ky = __uint_as_float(ckv.x & 0xffff0000u);
            float part = qx * kx + qy * ky;
            if (!USE_BIAS)
                part += cea.x * we4.x + cea.y * we4.y
                      + cea.z * we4.z + cea.w * we4.w;
            // 8-lane butterfly over aligned head group, pure VALU:
            part += dpp_mov<0xB1>(part);    // quad_perm [1,0,3,2]  (xor 1)
            part += dpp_mov<0x4E>(part);    // quad_perm [2,3,0,1]  (xor 2)
            part += dpp_mov<0x141>(part);   // row_half_mirror (quad<->quad)
            float ev = __expf(part + cb);   // cb==0 when !USE_BIAS (in part)
            denom += ev;
            accx = fmaf(ev, __uint_as_float(ckv.y << 16), accx);
            accy = fmaf(ev, __uint_as_float(ckv.y & 0xffff0000u), accy);
        }
    }

    float inv = denom > 0.f ? 1.f / denom : 0.f;
    *(float2*)(out + (size_t)d * 128 + lane * 2) = make_float2(accx * inv, accy * inv);
}

extern "C" void kernel_launch(void* const* d_in, const int* in_sizes, int n_in,
                              void* d_out, int out_size, void* d_ws, size_t ws_size,
                              hipStream_t stream) {
    const float* x          = (const float*)d_in[0];
    const int*   edge_index = (const int*)d_in[1];
    const float* edge_attr  = (const float*)d_in[2];
    const float* Wq         = (const float*)d_in[3];
    const float* Wk         = (const float*)d_in[4];
    const float* Wv         = (const float*)d_in[5];
    const float* We         = (const float*)d_in[6];
    float* out = (float*)d_out;

    const int N = in_sizes[0] / 128;
    const int E = in_sizes[1] / 2;

    // ws layout: q f32[N*128] | kvb u32[N*128] | perm int2[E] |
    //            counts,offsets,cursor[N] | blocksums,blockbase[256] |
    //            [pbias f32[E*8] iff it fits in ws_size]
    float* q = (float*)d_ws;
    uint32* kvb = (uint32*)(q + (size_t)N * 128);
    int2* perm = (int2*)(kvb + (size_t)N * 128);
    int* counts    = (int*)(perm + E);
    int* offsets   = counts + N;
    int* cursor    = offsets + N;
    int* blocksums = cursor + N;
    int* blockbase = blocksums + 256;
    float* pbias   = (float*)(blockbase + 256);

    const size_t need_bias =
        (size_t)((char*)(pbias + (size_t)E * 8) - (char*)d_ws);
    const bool use_bias = ws_size >= need_bias;

    hipMemsetAsync(counts, 0, (size_t)N * sizeof(int), stream);

    const int nxb_g = (N + 63) / 64;        // 1563 GEMM blocks
    const int nxb_h = (E + 1023) / 1024;    // 1563 histogram blocks
    const int nxb = nxb_g > nxb_h ? nxb_g : nxb_h;
    dim3 g1(nxb, 2);                        // y==0: GEMM, y==1: histogram
    qkv_count_kernel<<<g1, 256, 0, stream>>>(x, Wq, Wk, Wv, edge_index,
                                             q, kvb, counts, N, E);

    const int NB = (N + 511) / 512;  // 196
    scan_pass1<<<NB, 256, 0, stream>>>(counts, blocksums, N);
    scan_pass2<<<1, 256, 0, stream>>>(blocksums, blockbase, NB);
    scan_pass3<<<NB, 256, 0, stream>>>(counts, blockbase, offsets, cursor, N);

    if (use_bias)
        scatter_kernel<true><<<(E + 255) / 256, 256, 0, stream>>>(
            edge_index, edge_attr, We, cursor, perm, pbias, E);
    else
        scatter_kernel<false><<<(E + 255) / 256, 256, 0, stream>>>(
            edge_index, edge_attr, We, cursor, perm, pbias, E);

    if (use_bias)
        attn_fused_kernel<true><<<(N + 3) / 4, 256, 0, stream>>>(
            q, kvb, pbias, edge_attr, We, offsets, counts, perm, out, N);
    else
        attn_fused_kernel<false><<<(N + 3) / 4, 256, 0, stream>>>(
            q, kvb, pbias, edge_attr, We, offsets, counts, perm, out, N);
}